// Round 1
// baseline (770.740 us; speedup 1.0000x reference)
//
#include <hip/hip_runtime.h>

// Problem constants (fixed by reference setup_inputs):
//   x: (16, 3, 256, 256) fp32; w1: (16,3,3,3); w2: (16,16,3,3); w3: (64,16,3,3)
//   out: (16, 64, 256, 256) fp32, BatchNorm(train-mode, biased var) applied.
#define BATCH 16
#define WIDTH 256
#define HW 65536
#define C1IN 3
#define CMID 16
#define COUT 64
#define BN_EPS 1e-5f

// Workspace layout (in floats):
//   [0, 16.78M)           g2  (conv2 output, 16 ch)
//   [N_G2, +128)          stats: sum[64], sumsq[64]
//   then transposed weights wt1 [ci][k][co16], wt2 [ci][k][co16], wt3 [ci][k][co64]
#define N_G2 (CMID * BATCH * HW)      // 16,777,216 floats
#define OFF_STATS N_G2
#define OFF_WT1 (N_G2 + 128)
#define OFF_WT2 (OFF_WT1 + 448)       // wt1 needs 432, pad to 448
#define OFF_WT3 (OFF_WT2 + 2304)      // wt2 needs 2304
// total ws floats needed: OFF_WT3 + 9216  (~67.2 MB)

// ---------------------------------------------------------------------------
// init: zero stats + transpose weights to [ci][k][co] so the conv inner loops
// read contiguous wave-uniform addresses (-> merged s_load_dwordx16).
__global__ void init_kernel(const float* __restrict__ w1,
                            const float* __restrict__ w2,
                            const float* __restrict__ w3,
                            float* __restrict__ ws) {
  int i = blockIdx.x * 256 + threadIdx.x;
  if (i < 128) ws[OFF_STATS + i] = 0.0f;
  if (i < 16 * 27) {  // wt1[(ci*9+k)*16 + co] = w1[(co*3+ci)*9 + k]
    int co = i & 15, r = i >> 4;
    int ci = r / 9, k = r - ci * 9;
    ws[OFF_WT1 + i] = w1[(co * 3 + ci) * 9 + k];
  }
  if (i < 16 * 144) {  // wt2[(ci*9+k)*16 + co] = w2[(co*16+ci)*9 + k]
    int co = i & 15, r = i >> 4;
    int ci = r / 9, k = r - ci * 9;
    ws[OFF_WT2 + i] = w2[(co * 16 + ci) * 9 + k];
  }
  if (i < 64 * 144) {  // wt3[(ci*9+k)*64 + co] = w3[(co*16+ci)*9 + k]
    int co = i & 63, r = i >> 6;
    int ci = r / 9, k = r - ci * 9;
    ws[OFF_WT3 + i] = w3[(co * 16 + ci) * 9 + k];
  }
}

// ---------------------------------------------------------------------------
// conv1: 3 -> 16, 3x3 pad 1. One block = 16x16 output tile for one batch.
// LDS pitch 24: ty-groups hit bank offsets {0,24,16,8} -> exact 2-way (free).
__global__ __launch_bounds__(256) void conv1_kernel(const float* __restrict__ x,
                                                    const float* __restrict__ wt,
                                                    float* __restrict__ g1) {
  __shared__ float tile[C1IN][18][24];
  const int tx = threadIdx.x, ty = threadIdx.y;
  const int x0 = blockIdx.x * 16, y0 = blockIdx.y * 16, b = blockIdx.z;
  const int tid = ty * 16 + tx;
  const float* xb = x + (size_t)b * C1IN * HW;
  for (int i = tid; i < C1IN * 18 * 18; i += 256) {
    int ci = i / 324, r = i - ci * 324;
    int yy = r / 18, xx = r - yy * 18;
    int gy = y0 + yy - 1, gx = x0 + xx - 1;
    float v = 0.0f;
    if ((unsigned)gy < 256u && (unsigned)gx < 256u) v = xb[ci * HW + gy * WIDTH + gx];
    tile[ci][yy][xx] = v;
  }
  __syncthreads();

  float acc[CMID] = {};
#pragma unroll
  for (int ci = 0; ci < C1IN; ci++) {
#pragma unroll
    for (int k = 0; k < 9; k++) {
      const float v = tile[ci][ty + k / 3][tx + k % 3];
      const float* wp = wt + (ci * 9 + k) * CMID;  // uniform -> s_load
#pragma unroll
      for (int co = 0; co < CMID; co++) acc[co] = fmaf(v, wp[co], acc[co]);
    }
  }
  float* ob = g1 + (size_t)b * CMID * HW + (y0 + ty) * WIDTH + (x0 + tx);
#pragma unroll
  for (int co = 0; co < CMID; co++) ob[co * HW] = acc[co];
}

// ---------------------------------------------------------------------------
// conv2: 16 -> 16
__global__ __launch_bounds__(256) void conv2_kernel(const float* __restrict__ g1,
                                                    const float* __restrict__ wt,
                                                    float* __restrict__ g2) {
  __shared__ float tile[CMID][18][24];
  const int tx = threadIdx.x, ty = threadIdx.y;
  const int x0 = blockIdx.x * 16, y0 = blockIdx.y * 16, b = blockIdx.z;
  const int tid = ty * 16 + tx;
  const float* gb = g1 + (size_t)b * CMID * HW;
  for (int i = tid; i < CMID * 18 * 18; i += 256) {
    int ci = i / 324, r = i - ci * 324;
    int yy = r / 18, xx = r - yy * 18;
    int gy = y0 + yy - 1, gx = x0 + xx - 1;
    float v = 0.0f;
    if ((unsigned)gy < 256u && (unsigned)gx < 256u) v = gb[ci * HW + gy * WIDTH + gx];
    tile[ci][yy][xx] = v;
  }
  __syncthreads();

  float acc[CMID] = {};
  for (int ci = 0; ci < CMID; ci++) {
#pragma unroll
    for (int k = 0; k < 9; k++) {
      const float v = tile[ci][ty + k / 3][tx + k % 3];
      const float* wp = wt + (ci * 9 + k) * CMID;
#pragma unroll
      for (int co = 0; co < CMID; co++) acc[co] = fmaf(v, wp[co], acc[co]);
    }
  }
  float* ob = g2 + (size_t)b * CMID * HW + (y0 + ty) * WIDTH + (x0 + tx);
#pragma unroll
  for (int co = 0; co < CMID; co++) ob[co * HW] = acc[co];
}

// ---------------------------------------------------------------------------
// conv3: 16 -> 64. 64 fp32 accumulators per thread.
__global__ __launch_bounds__(256) void conv3_kernel(const float* __restrict__ g2,
                                                    const float* __restrict__ wt,
                                                    float* __restrict__ h) {
  __shared__ float tile[CMID][18][24];
  const int tx = threadIdx.x, ty = threadIdx.y;
  const int x0 = blockIdx.x * 16, y0 = blockIdx.y * 16, b = blockIdx.z;
  const int tid = ty * 16 + tx;
  const float* gb = g2 + (size_t)b * CMID * HW;
  for (int i = tid; i < CMID * 18 * 18; i += 256) {
    int ci = i / 324, r = i - ci * 324;
    int yy = r / 18, xx = r - yy * 18;
    int gy = y0 + yy - 1, gx = x0 + xx - 1;
    float v = 0.0f;
    if ((unsigned)gy < 256u && (unsigned)gx < 256u) v = gb[ci * HW + gy * WIDTH + gx];
    tile[ci][yy][xx] = v;
  }
  __syncthreads();

  float acc[COUT] = {};
  for (int ci = 0; ci < CMID; ci++) {
#pragma unroll
    for (int k = 0; k < 9; k++) {
      const float v = tile[ci][ty + k / 3][tx + k % 3];
      const float* wp = wt + (ci * 9 + k) * COUT;  // 64 contiguous uniform floats
#pragma unroll
      for (int co = 0; co < COUT; co++) acc[co] = fmaf(v, wp[co], acc[co]);
    }
  }
  float* ob = h + (size_t)b * COUT * HW + (y0 + ty) * WIDTH + (x0 + tx);
#pragma unroll
  for (int co = 0; co < COUT; co++) ob[co * HW] = acc[co];
}

// ---------------------------------------------------------------------------
// stats: one block per (b,c) plane; 2 atomics per block into stats[].
__global__ __launch_bounds__(256) void stats_kernel(const float* __restrict__ h,
                                                    float* __restrict__ stats) {
  const int plane = blockIdx.x;        // b*64 + c
  const int c = plane & 63;
  const float4* p = (const float4*)(h + (size_t)plane * HW);
  float s = 0.0f, q = 0.0f;
  for (int i = threadIdx.x; i < HW / 4; i += 256) {
    float4 v = p[i];
    s += v.x + v.y + v.z + v.w;
    q += v.x * v.x + v.y * v.y + v.z * v.z + v.w * v.w;
  }
#pragma unroll
  for (int off = 32; off; off >>= 1) {
    s += __shfl_xor(s, off);
    q += __shfl_xor(q, off);
  }
  __shared__ float ls[4], lq[4];
  const int wave = threadIdx.x >> 6;
  if ((threadIdx.x & 63) == 0) { ls[wave] = s; lq[wave] = q; }
  __syncthreads();
  if (threadIdx.x == 0) {
    float S = ls[0] + ls[1] + ls[2] + ls[3];
    float Q = lq[0] + lq[1] + lq[2] + lq[3];
    atomicAdd(&stats[c], S);
    atomicAdd(&stats[64 + c], Q);
  }
}

// ---------------------------------------------------------------------------
// bn: in-place normalize d_out with batch stats, gamma, beta.
__global__ __launch_bounds__(256) void bn_kernel(float* __restrict__ h,
                                                 const float* __restrict__ stats,
                                                 const float* __restrict__ gamma,
                                                 const float* __restrict__ beta) {
  const int plane = blockIdx.x;  // b*64 + c
  const int c = plane & 63;
  const float invN = 1.0f / (float)(BATCH * HW);
  const float mean = stats[c] * invN;
  const float var = stats[64 + c] * invN - mean * mean;
  const float scale = gamma[c] * rsqrtf(var + BN_EPS);
  const float shift = beta[c] - mean * scale;
  float4* p = (float4*)(h + (size_t)plane * HW);
  for (int i = threadIdx.x; i < HW / 4; i += 256) {
    float4 v = p[i];
    v.x = fmaf(v.x, scale, shift);
    v.y = fmaf(v.y, scale, shift);
    v.z = fmaf(v.z, scale, shift);
    v.w = fmaf(v.w, scale, shift);
    p[i] = v;
  }
}

// ---------------------------------------------------------------------------
extern "C" void kernel_launch(void* const* d_in, const int* in_sizes, int n_in,
                              void* d_out, int out_size, void* d_ws, size_t ws_size,
                              hipStream_t stream) {
  const float* x = (const float*)d_in[0];
  const float* w1 = (const float*)d_in[1];
  const float* w2 = (const float*)d_in[2];
  const float* w3 = (const float*)d_in[3];
  const float* gamma = (const float*)d_in[4];
  const float* beta = (const float*)d_in[5];
  float* out = (float*)d_out;
  float* ws = (float*)d_ws;

  float* g1 = out;            // reuse first 67 MB of d_out; conv3 overwrites later
  float* g2 = ws;             // 67 MB in workspace
  float* stats = ws + OFF_STATS;

  init_kernel<<<36, 256, 0, stream>>>(w1, w2, w3, ws);

  dim3 blk(16, 16);
  dim3 grd(16, 16, BATCH);
  conv1_kernel<<<grd, blk, 0, stream>>>(x, ws + OFF_WT1, g1);
  conv2_kernel<<<grd, blk, 0, stream>>>(g1, ws + OFF_WT2, g2);
  conv3_kernel<<<grd, blk, 0, stream>>>(g2, ws + OFF_WT3, out);
  stats_kernel<<<1024, 256, 0, stream>>>(out, stats);
  bn_kernel<<<1024, 256, 0, stream>>>(out, stats, gamma, beta);
}

// Round 2
// 558.622 us; speedup vs baseline: 1.3797x; 1.3797x over previous
//
#include <hip/hip_runtime.h>

// x: (16,3,256,256) fp32; w1: (16,3,3,3); w2: (16,16,3,3); w3: (64,16,3,3)
// out: (16,64,256,256) fp32 with train-mode BatchNorm (biased var).
#define BATCH 16
#define WIDTH 256
#define HW 65536
#define C1IN 3
#define CMID 16
#define COUT 64
#define BN_EPS 1e-5f

// Workspace layout (float units):
#define N_G2 (CMID * BATCH * HW)          // 16,777,216 floats: conv2 output
#define OFF_STATS N_G2                    // 128 floats: sum[64], sumsq[64]
#define OFF_WT1 (N_G2 + 128)              // 432 -> pad 448 (fp32, conv1)
#define OFF_WT2 (OFF_WT1 + 448)           // 2304 (fp32, conv2)
#define OFF_WT3H (OFF_WT2 + 2304)         // ushort[64*160] = 5120 floats (bf16 hi)
#define OFF_WT3L (OFF_WT3H + 5120)        // ushort[64*160] = 5120 floats (bf16 lo)
#define OFF_PART (OFF_WT3L + 5120)        // float[128*4096], layout [stat][block]
#define WS_FLOATS_NEEDED (OFF_PART + 128 * 4096)

#define CIP 24                            // ci pitch (ushorts) in conv3 LDS tile
#define ROWP (18 * CIP)                   // 432 ushorts per tile row

typedef __attribute__((ext_vector_type(8))) short bf16x8;
typedef __attribute__((ext_vector_type(4))) float f32x4;

__device__ __forceinline__ ushort f2bf(float f) {
  unsigned u = __float_as_uint(f);
  u += 0x7FFFu + ((u >> 16) & 1u);        // round-to-nearest-even
  return (ushort)(u >> 16);
}
__device__ __forceinline__ float bf2f(ushort h) {
  return __uint_as_float(((unsigned)h) << 16);
}

// ---------------------------------------------------------------------------
// init: zero stats + fp32 transposed weights for conv1/2 + bf16 hi/lo split
// weights for conv3 in [co][k=tap*16+ci] with K padded 144->160 (tap 9 = 0).
__global__ void init_kernel(const float* __restrict__ w1,
                            const float* __restrict__ w2,
                            const float* __restrict__ w3,
                            float* __restrict__ ws) {
  int i = blockIdx.x * 256 + threadIdx.x;
  if (i < 128) ws[OFF_STATS + i] = 0.0f;
  if (i < 16 * 27) {
    int co = i & 15, r = i >> 4;
    int ci = r / 9, k = r - ci * 9;
    ws[OFF_WT1 + i] = w1[(co * 3 + ci) * 9 + k];
  }
  if (i < 16 * 144) {
    int co = i & 15, r = i >> 4;
    int ci = r / 9, k = r - ci * 9;
    ws[OFF_WT2 + i] = w2[(co * 16 + ci) * 9 + k];
  }
  if (i < 64 * 160) {
    ushort* wh = (ushort*)(ws + OFF_WT3H);
    ushort* wl = (ushort*)(ws + OFF_WT3L);
    int co = i / 160, k = i - co * 160;
    int tap = k >> 4, ci = k & 15;
    float v = (tap < 9) ? w3[(co * 16 + ci) * 9 + tap] : 0.0f;
    ushort hi = f2bf(v);
    wh[i] = hi;
    wl[i] = f2bf(v - bf2f(hi));
  }
}

// ---------------------------------------------------------------------------
// conv1: 3 -> 16 (fp32 vector; cheap)
__global__ __launch_bounds__(256) void conv1_kernel(const float* __restrict__ x,
                                                    const float* __restrict__ wt,
                                                    float* __restrict__ g1) {
  __shared__ float tile[C1IN][18][24];
  const int tx = threadIdx.x, ty = threadIdx.y;
  const int x0 = blockIdx.x * 16, y0 = blockIdx.y * 16, b = blockIdx.z;
  const int tid = ty * 16 + tx;
  const float* xb = x + (size_t)b * C1IN * HW;
  for (int i = tid; i < C1IN * 324; i += 256) {
    int ci = i / 324, r = i - ci * 324;
    int yy = r / 18, xx = r - yy * 18;
    int gy = y0 + yy - 1, gx = x0 + xx - 1;
    float v = 0.0f;
    if ((unsigned)gy < 256u && (unsigned)gx < 256u) v = xb[ci * HW + gy * WIDTH + gx];
    tile[ci][yy][xx] = v;
  }
  __syncthreads();
  float acc[CMID] = {};
#pragma unroll
  for (int ci = 0; ci < C1IN; ci++) {
#pragma unroll
    for (int k = 0; k < 9; k++) {
      const float v = tile[ci][ty + k / 3][tx + k % 3];
      const float* wp = wt + (ci * 9 + k) * CMID;
#pragma unroll
      for (int co = 0; co < CMID; co++) acc[co] = fmaf(v, wp[co], acc[co]);
    }
  }
  float* ob = g1 + (size_t)b * CMID * HW + (y0 + ty) * WIDTH + (x0 + tx);
#pragma unroll
  for (int co = 0; co < CMID; co++) ob[co * HW] = acc[co];
}

// ---------------------------------------------------------------------------
// conv2: 16 -> 16 (fp32 vector)
__global__ __launch_bounds__(256) void conv2_kernel(const float* __restrict__ g1,
                                                    const float* __restrict__ wt,
                                                    float* __restrict__ g2) {
  __shared__ float tile[CMID][18][24];
  const int tx = threadIdx.x, ty = threadIdx.y;
  const int x0 = blockIdx.x * 16, y0 = blockIdx.y * 16, b = blockIdx.z;
  const int tid = ty * 16 + tx;
  const float* gb = g1 + (size_t)b * CMID * HW;
  for (int i = tid; i < CMID * 324; i += 256) {
    int ci = i / 324, r = i - ci * 324;
    int yy = r / 18, xx = r - yy * 18;
    int gy = y0 + yy - 1, gx = x0 + xx - 1;
    float v = 0.0f;
    if ((unsigned)gy < 256u && (unsigned)gx < 256u) v = gb[ci * HW + gy * WIDTH + gx];
    tile[ci][yy][xx] = v;
  }
  __syncthreads();
  float acc[CMID] = {};
  for (int ci = 0; ci < CMID; ci++) {
#pragma unroll
    for (int k = 0; k < 9; k++) {
      const float v = tile[ci][ty + k / 3][tx + k % 3];
      const float* wp = wt + (ci * 9 + k) * CMID;
#pragma unroll
      for (int co = 0; co < CMID; co++) acc[co] = fmaf(v, wp[co], acc[co]);
    }
  }
  float* ob = g2 + (size_t)b * CMID * HW + (y0 + ty) * WIDTH + (x0 + tx);
#pragma unroll
  for (int co = 0; co < CMID; co++) ob[co * HW] = acc[co];
}

// ---------------------------------------------------------------------------
// conv3: 16 -> 64 via MFMA implicit GEMM, bf16 hi/lo split (3 products).
// Block: 256 thr = 4 waves, one batch, 16x16 spatial tile, all 64 co.
// Wave (wc = w&1, wp = w>>1): co = wc*32..+31 (2 co-tiles), rows wp*8..+7.
// K = 160 = 10 taps x 16 ci (tap 9 zero-padded in weights).
// A-frag (weights): lane holds W[co = base + (lane&15)][k = (lane>>4)*8 + j].
// B-frag (patch):   lane holds P[k = (lane>>4)*8 + j][px = lane&15].
// D: row (=co sub-idx) = (lane>>4)*4 + j, col (=px) = lane&15.   [m89 layout]
__global__ __launch_bounds__(256, 2) void conv3_mfma(
    const float* __restrict__ g2, const ushort* __restrict__ w3h,
    const ushort* __restrict__ w3l, float* __restrict__ h,
    float* __restrict__ part) {
  __shared__ ushort th[18 * ROWP / 18 * 18];  // 18*18*CIP = 7776
  __shared__ ushort tl[7776];
  const int tid = threadIdx.x;
  const int lane = tid & 63;
  const int w = tid >> 6;
  const int wc = w & 1, wp = w >> 1;
  const int x0 = blockIdx.x * 16, y0 = blockIdx.y * 16, b = blockIdx.z;

  // ---- stage conv2 tile as channel-last bf16 hi/lo ----
  const float* gb = g2 + (size_t)b * CMID * HW;
  for (int i = tid; i < 4 * 324; i += 256) {   // (ciq 0..3, pixel 0..323)
    int ciq = i / 324, r = i - ciq * 324;
    int yy = r / 18, xx = r - yy * 18;
    int gy = y0 + yy - 1, gx = x0 + xx - 1;
    bool ok = ((unsigned)gy < 256u) & ((unsigned)gx < 256u);
    int cb = ciq * 4;
    ushort hs[4], ls[4];
#pragma unroll
    for (int q = 0; q < 4; q++) {
      float v = ok ? gb[(cb + q) * HW + gy * WIDTH + gx] : 0.0f;
      ushort hi = f2bf(v);
      hs[q] = hi;
      ls[q] = f2bf(v - bf2f(hi));
    }
    int a = (yy * 18 + xx) * CIP + cb;           // 8B aligned
    *(ushort4*)(&th[a]) = make_ushort4(hs[0], hs[1], hs[2], hs[3]);
    *(ushort4*)(&tl[a]) = make_ushort4(ls[0], ls[1], ls[2], ls[3]);
  }

  // ---- A fragments (weights) from global, resident in VGPRs ----
  bf16x8 ah[2][5], al[2][5];
  {
    const int arow = lane & 15, ag = lane >> 4;
#pragma unroll
    for (int ct = 0; ct < 2; ct++) {
      int co = wc * 32 + ct * 16 + arow;
      const ushort* ph = w3h + co * 160 + ag * 8;
      const ushort* pl = w3l + co * 160 + ag * 8;
#pragma unroll
      for (int s = 0; s < 5; s++) {
        ah[ct][s] = *(const bf16x8*)(ph + s * 32);
        al[ct][s] = *(const bf16x8*)(pl + s * 32);
      }
    }
  }
  __syncthreads();

  // ---- per-lane B read offsets: k-group g -> (tap = 2s + (g>>1), cig = g&1)
  const int xx = lane & 15;
  const int g = lane >> 4;
  const int cig = g & 1, tg = g >> 1;
  int boff[5];
#pragma unroll
  for (int s = 0; s < 5; s++) {
    int tap = 2 * s + tg;                        // 0..9 (9 = zero-weight pad)
    int dy = (tap < 9) ? (tap / 3) : 0;
    int dx = (tap < 9) ? (tap - dy * 3) : 0;
    boff[s] = (dy * 18 + xx + dx) * CIP + cig * 8;
  }
  const int rbase = wp * 8;

  f32x4 acc[8][2] = {};
#pragma unroll
  for (int r = 0; r < 8; r++) {
    const int rowoff = (rbase + r) * ROWP;
#pragma unroll
    for (int s = 0; s < 5; s++) {
      bf16x8 bh = *(const bf16x8*)(th + rowoff + boff[s]);
      bf16x8 bl = *(const bf16x8*)(tl + rowoff + boff[s]);
#pragma unroll
      for (int ct = 0; ct < 2; ct++) {
        acc[r][ct] = __builtin_amdgcn_mfma_f32_16x16x32_bf16(ah[ct][s], bh, acc[r][ct], 0, 0, 0);
        acc[r][ct] = __builtin_amdgcn_mfma_f32_16x16x32_bf16(al[ct][s], bh, acc[r][ct], 0, 0, 0);
        acc[r][ct] = __builtin_amdgcn_mfma_f32_16x16x32_bf16(ah[ct][s], bl, acc[r][ct], 0, 0, 0);
      }
    }
  }

  // ---- write output ----
  const int colx = x0 + xx;
#pragma unroll
  for (int r = 0; r < 8; r++) {
    const int y = y0 + rbase + r;
#pragma unroll
    for (int ct = 0; ct < 2; ct++) {
      const int cob = wc * 32 + ct * 16 + g * 4;
      size_t p0 = ((size_t)b * COUT + cob) * HW + (size_t)y * WIDTH + colx;
#pragma unroll
      for (int j = 0; j < 4; j++) h[p0 + (size_t)j * HW] = acc[r][ct][j];
    }
  }

  // ---- fused BN partial sums (per-block, no global atomics) ----
  if (part) {
    __syncthreads();                 // done reading th/tl; reuse as float[128]
    float* pp = (float*)th;
    for (int i = tid; i < 128; i += 256) pp[i] = 0.0f;
    __syncthreads();
#pragma unroll
    for (int ct = 0; ct < 2; ct++) {
#pragma unroll
      for (int j = 0; j < 4; j++) {
        float s = 0.0f, q = 0.0f;
#pragma unroll
        for (int r = 0; r < 8; r++) {
          float v = acc[r][ct][j];
          s += v;
          q += v * v;
        }
        // reduce across the 16 lanes sharing g (xor bits 0..3 stay in-group)
        s += __shfl_xor(s, 1); q += __shfl_xor(q, 1);
        s += __shfl_xor(s, 2); q += __shfl_xor(q, 2);
        s += __shfl_xor(s, 4); q += __shfl_xor(q, 4);
        s += __shfl_xor(s, 8); q += __shfl_xor(q, 8);
        if (xx == 0) {
          int co = wc * 32 + ct * 16 + g * 4 + j;
          atomicAdd(&pp[co], s);
          atomicAdd(&pp[64 + co], q);
        }
      }
    }
    __syncthreads();
    const int blk = blockIdx.x + (blockIdx.y << 4) + (blockIdx.z << 8);
    if (tid < 128) part[tid * 4096 + blk] = pp[tid];
  }
}

// ---------------------------------------------------------------------------
// reduce block partials -> stats[128]
__global__ __launch_bounds__(256) void reduce_part(const float* __restrict__ part,
                                                   float* __restrict__ stats) {
  const int i = blockIdx.x;  // 0..127
  float s = 0.0f;
  for (int b = threadIdx.x; b < 4096; b += 256) s += part[i * 4096 + b];
#pragma unroll
  for (int off = 32; off; off >>= 1) s += __shfl_xor(s, off);
  __shared__ float ls[4];
  if ((threadIdx.x & 63) == 0) ls[threadIdx.x >> 6] = s;
  __syncthreads();
  if (threadIdx.x == 0) stats[i] = ls[0] + ls[1] + ls[2] + ls[3];
}

// ---------------------------------------------------------------------------
// fallback stats over full tensor (used only if ws is too small for partials)
__global__ __launch_bounds__(256) void stats_kernel(const float* __restrict__ h,
                                                    float* __restrict__ stats) {
  const int plane = blockIdx.x;
  const int c = plane & 63;
  const float4* p = (const float4*)(h + (size_t)plane * HW);
  float s = 0.0f, q = 0.0f;
  for (int i = threadIdx.x; i < HW / 4; i += 256) {
    float4 v = p[i];
    s += v.x + v.y + v.z + v.w;
    q += v.x * v.x + v.y * v.y + v.z * v.z + v.w * v.w;
  }
#pragma unroll
  for (int off = 32; off; off >>= 1) {
    s += __shfl_xor(s, off);
    q += __shfl_xor(q, off);
  }
  __shared__ float ls[4], lq[4];
  const int wave = threadIdx.x >> 6;
  if ((threadIdx.x & 63) == 0) { ls[wave] = s; lq[wave] = q; }
  __syncthreads();
  if (threadIdx.x == 0) {
    atomicAdd(&stats[c], ls[0] + ls[1] + ls[2] + ls[3]);
    atomicAdd(&stats[64 + c], lq[0] + lq[1] + lq[2] + lq[3]);
  }
}

// ---------------------------------------------------------------------------
// bn: in-place normalize
__global__ __launch_bounds__(256) void bn_kernel(float* __restrict__ h,
                                                 const float* __restrict__ stats,
                                                 const float* __restrict__ gamma,
                                                 const float* __restrict__ beta) {
  const int plane = blockIdx.x;
  const int c = plane & 63;
  const float invN = 1.0f / (float)(BATCH * HW);
  const float mean = stats[c] * invN;
  const float var = stats[64 + c] * invN - mean * mean;
  const float scale = gamma[c] * rsqrtf(var + BN_EPS);
  const float shift = beta[c] - mean * scale;
  float4* p = (float4*)(h + (size_t)plane * HW);
  for (int i = threadIdx.x; i < HW / 4; i += 256) {
    float4 v = p[i];
    v.x = fmaf(v.x, scale, shift);
    v.y = fmaf(v.y, scale, shift);
    v.z = fmaf(v.z, scale, shift);
    v.w = fmaf(v.w, scale, shift);
    p[i] = v;
  }
}

// ---------------------------------------------------------------------------
extern "C" void kernel_launch(void* const* d_in, const int* in_sizes, int n_in,
                              void* d_out, int out_size, void* d_ws, size_t ws_size,
                              hipStream_t stream) {
  const float* x = (const float*)d_in[0];
  const float* w1 = (const float*)d_in[1];
  const float* w2 = (const float*)d_in[2];
  const float* w3 = (const float*)d_in[3];
  const float* gamma = (const float*)d_in[4];
  const float* beta = (const float*)d_in[5];
  float* out = (float*)d_out;
  float* ws = (float*)d_ws;

  float* g1 = out;                       // staged in (later overwritten) d_out
  float* g2 = ws;
  float* stats = ws + OFF_STATS;
  const ushort* w3h = (const ushort*)(ws + OFF_WT3H);
  const ushort* w3l = (const ushort*)(ws + OFF_WT3L);
  const bool use_part = ws_size >= (size_t)WS_FLOATS_NEEDED * sizeof(float);
  float* part = use_part ? (ws + OFF_PART) : nullptr;

  init_kernel<<<40, 256, 0, stream>>>(w1, w2, w3, ws);

  dim3 blk(16, 16);
  dim3 grd(16, 16, BATCH);
  conv1_kernel<<<grd, blk, 0, stream>>>(x, ws + OFF_WT1, g1);
  conv2_kernel<<<grd, blk, 0, stream>>>(g1, ws + OFF_WT2, g2);
  conv3_mfma<<<grd, dim3(256), 0, stream>>>(g2, w3h, w3l, out, part);
  if (use_part) {
    reduce_part<<<128, 256, 0, stream>>>(part, stats);
  } else {
    stats_kernel<<<1024, 256, 0, stream>>>(out, stats);
  }
  bn_kernel<<<1024, 256, 0, stream>>>(out, stats, gamma, beta);
}